// Round 3
// baseline (540.595 us; speedup 1.0000x reference)
//
#include <hip/hip_runtime.h>
#include <hip/hip_bf16.h>
#include <stdint.h>

// Problem constants (from reference setup_inputs)
#define NB 8
#define NA 49104
#define NC 90
#define NM 32
#define FEPS 1e-4f
#define CHUNKS_IMG (NA * NC / 4)   // 1,104,840 float4 chunks per image
#define LN2_HALF 0.34657359027997264f  // 0.5 * ln(2)

typedef float f32x4 __attribute__((ext_vector_type(4)));

// ws layout (header zeroed each launch):
//   [0,64)     double reg_sum[8]
//   [64,128)   double cls_sum[8]
//   [128,192)  double corr[8]
//   [192,224)  int    npos[8]
//   [224,228)  int    pos_count
//   [256, +4*(NB*NA+16))          float    wa[NB*NA + 16]  (0/1 per anchor, padded)
//   [wa_end, +4*NB*NA)            uint32_t pos_list

// ---------------------------------------------------------------------------
// Kernel A: per-anchor IoU assignment. Writes wa (0/1), pos_list (compact),
// npos, and smooth-L1 regression sum.
// ---------------------------------------------------------------------------
__global__ __launch_bounds__(256) void fl_assign(
    const float* __restrict__ anchors,      // [NA,4] (y1,x1,y2,x2)
    const float* __restrict__ regressions,  // [NB,NA,4]
    const float* __restrict__ annotations,  // [NB,NM,5] (x1,y1,x2,y2,label)
    double* __restrict__ reg_sum,           // [NB]
    int* __restrict__ npos,                 // [NB]
    int* __restrict__ pos_count,
    float* __restrict__ wa,                 // [NB*NA + pad]
    uint32_t* __restrict__ pos_list)
{
    const int b = blockIdx.y;
    const int a = blockIdx.x * 256 + threadIdx.x;

    __shared__ float s_ann[NM * 5];
    if (threadIdx.x < NM * 5)
        s_ann[threadIdx.x] = annotations[b * NM * 5 + threadIdx.x];
    __syncthreads();

    float rsum = 0.0f;
    int pcnt = 0;
    bool pos = false;
    uint32_t enc = 0;

    if (a < NA) {
        const f32x4 av = ((const f32x4*)anchors)[a];
        const float ay1 = av.x, ax1 = av.y, ay2 = av.z, ax2 = av.w;
        const float aw = ax2 - ax1, ah = ay2 - ay1;
        const float aarea = aw * ah;

        float best = -2.0f;   // invalid gt iou = -1; strict > keeps first argmax
        int bm = 0;
        #pragma unroll 4
        for (int m = 0; m < NM; ++m) {
            const float bx1 = s_ann[m * 5 + 0];
            const float by1 = s_ann[m * 5 + 1];
            const float bx2 = s_ann[m * 5 + 2];
            const float by2 = s_ann[m * 5 + 3];
            const float lab = s_ann[m * 5 + 4];
            const float area = (bx2 - bx1) * (by2 - by1);
            float iw = fminf(ax2, bx2) - fmaxf(ax1, bx1);
            float ih = fminf(ay2, by2) - fmaxf(ay1, by1);
            iw = fmaxf(iw, 0.0f);
            ih = fmaxf(ih, 0.0f);
            const float inter = iw * ih;
            const float ua = fmaxf(aarea + area - inter, 1e-8f);
            float iou = inter / ua;
            if (lab == -1.0f) iou = -1.0f;
            if (iou > best) { best = iou; bm = m; }
        }

        pos = best >= 0.5f;
        const bool bz = (best < 0.4f) || pos;      // non-ignored anchor
        const int lbl = ((int)s_ann[bm * 5 + 4]) & 0x7f;
        wa[b * NA + a] = bz ? 1.0f : 0.0f;
        enc = ((uint32_t)(b * NA + a) << 7) | (uint32_t)lbl;

        if (pos) {
            pcnt = 1;
            const float bx1 = s_ann[bm * 5 + 0];
            const float by1 = s_ann[bm * 5 + 1];
            const float bx2 = s_ann[bm * 5 + 2];
            const float by2 = s_ann[bm * 5 + 3];
            float gw = bx2 - bx1, gh = by2 - by1;
            const float gcx = bx1 + 0.5f * gw;
            const float gcy = by1 + 0.5f * gh;    // cx/cy use unclipped w/h
            gw = fmaxf(gw, 1.0f);
            gh = fmaxf(gh, 1.0f);
            const float acx = ax1 + 0.5f * aw;
            const float acy = ay1 + 0.5f * ah;

            const f32x4 rv = ((const f32x4*)regressions)[(size_t)b * NA + a];
            const float t0 = (gcy - acy) / ah;
            const float t1 = (gcx - acx) / aw;
            const float t2 = logf(gh / ah);
            const float t3 = logf(gw / aw);

            float d;
            d = fabsf(t0 - rv.x); rsum += (d <= 1.0f/9.0f) ? 4.5f*d*d : d - 1.0f/18.0f;
            d = fabsf(t1 - rv.y); rsum += (d <= 1.0f/9.0f) ? 4.5f*d*d : d - 1.0f/18.0f;
            d = fabsf(t2 - rv.z); rsum += (d <= 1.0f/9.0f) ? 4.5f*d*d : d - 1.0f/18.0f;
            d = fabsf(t3 - rv.w); rsum += (d <= 1.0f/9.0f) ? 4.5f*d*d : d - 1.0f/18.0f;
        }
    }

    // wave-aggregated positive-list append
    {
        const int lane = threadIdx.x & 63;
        const unsigned long long m = __ballot(pos);
        const int cnt = __popcll(m);
        if (cnt) {
            const int leader = __ffsll(m) - 1;
            int base = 0;
            if (lane == leader) base = atomicAdd(pos_count, cnt);
            base = __shfl(base, leader);
            if (pos) {
                const int off = __popcll(m & ((1ull << lane) - 1ull));
                pos_list[base + off] = enc;
            }
        }
    }

    // block reduce (4 waves of 64)
    #pragma unroll
    for (int off = 32; off > 0; off >>= 1) {
        rsum += __shfl_down(rsum, off);
        pcnt += __shfl_down(pcnt, off);
    }
    __shared__ float s_r[4];
    __shared__ int s_p[4];
    const int wave = threadIdx.x >> 6;
    if ((threadIdx.x & 63) == 0) { s_r[wave] = rsum; s_p[wave] = pcnt; }
    __syncthreads();
    if (threadIdx.x == 0) {
        const float r = s_r[0] + s_r[1] + s_r[2] + s_r[3];
        const int p = s_p[0] + s_p[1] + s_p[2] + s_p[3];
        if (p) atomicAdd(&npos[b], p);
        if (r != 0.0f) atomicAdd(&reg_sum[b], (double)r);
    }
}

// ---------------------------------------------------------------------------
// Kernel B: main focal pass. Every element treated as t=0 weighted by wa.
// Grid (1079, NB), block 256. Each thread: 4 independent float4 NT loads.
// acc accumulates  wa * p^2 * log2(1-p); scaled by -0.5*ln2 at the atomic.
// ---------------------------------------------------------------------------
__global__ __launch_bounds__(256) void fl_focal(
    const f32x4* __restrict__ cls,
    const float* __restrict__ wa,
    double* __restrict__ cls_sum)
{
    const int b = blockIdx.y;
    const f32x4* cb = cls + (size_t)b * CHUNKS_IMG;
    const float* wb = wa + b * NA;

    const int i0 = blockIdx.x * 1024 + threadIdx.x;

    int   idx[4];
    float okf[4];
    f32x4 v[4];
    #pragma unroll
    for (int u = 0; u < 4; ++u) {
        idx[u] = i0 + u * 256;
        okf[u] = (idx[u] < CHUNKS_IMG) ? 1.0f : 0.0f;
        const int ic = (idx[u] < CHUNKS_IMG) ? idx[u] : (CHUNKS_IMG - 1);
        v[u] = __builtin_nontemporal_load(&cb[ic]);
        idx[u] = ic;
    }

    // per-chunk anchor ids + wa gathers (issued before the transcendental chain)
    int   c0[4];
    float w0[4], w1[4];
    #pragma unroll
    for (int u = 0; u < 4; ++u) {
        const uint32_t e0 = (uint32_t)idx[u] * 4u;
        const uint32_t aid = e0 / 90u;          // magic-mul division
        c0[u] = (int)(e0 - aid * 90u);
        w0[u] = wb[aid] * okf[u];
        w1[u] = wb[aid + 1] * okf[u];           // padded; may read next image (unused)
    }

    float acc = 0.0f;
    #pragma unroll
    for (int u = 0; u < 4; ++u) {
        const float pv[4] = {v[u].x, v[u].y, v[u].z, v[u].w};
        #pragma unroll
        for (int j = 0; j < 4; ++j) {
            float p = fminf(fmaxf(pv[j], FEPS), 1.0f - FEPS);
            const float l = __log2f(1.0f - p);
            const float w = (c0[u] + j < 90) ? w0[u] : w1[u];
            acc = fmaf(p * p * l, w, acc);
        }
    }

    #pragma unroll
    for (int off = 32; off > 0; off >>= 1)
        acc += __shfl_down(acc, off);
    __shared__ float s_r[4];
    const int wave = threadIdx.x >> 6;
    if ((threadIdx.x & 63) == 0) s_r[wave] = acc;
    __syncthreads();
    if (threadIdx.x == 0) {
        const float r = s_r[0] + s_r[1] + s_r[2] + s_r[3];
        atomicAdd(&cls_sum[b], (double)r * -(double)LN2_HALF);
    }
}

// ---------------------------------------------------------------------------
// Kernel C: correction for positive anchors' labeled class:
//   + 0.5(1-p)^2(-log p)  - 0.5 p^2(-log(1-p))
// ---------------------------------------------------------------------------
__global__ __launch_bounds__(256) void fl_posfix(
    const float* __restrict__ cls,
    const uint32_t* __restrict__ pos_list,
    const int* __restrict__ pos_count,
    double* __restrict__ corr)
{
    const int n = *pos_count;
    for (int i = blockIdx.x * blockDim.x + threadIdx.x; i < n;
         i += gridDim.x * blockDim.x) {
        const uint32_t e = pos_list[i];
        const int lbl = (int)(e & 0x7fu);
        const uint32_t idx = e >> 7;           // b*NA + a
        const int b = (int)(idx / (uint32_t)NA);
        float p = cls[(size_t)idx * NC + lbl];
        p = fminf(fmaxf(p, FEPS), 1.0f - FEPS);
        const float q = 1.0f - p;
        const float delta = 0.5f * q * q * (-logf(p)) - 0.5f * p * p * (-logf(q));
        atomicAdd(&corr[b], (double)delta);
    }
}

// ---------------------------------------------------------------------------
// Kernel D: finalize
// ---------------------------------------------------------------------------
__global__ void fl_final(
    const double* __restrict__ reg_sum,
    const double* __restrict__ cls_sum,
    const double* __restrict__ corr,
    const int* __restrict__ npos,
    float* __restrict__ out)
{
    if (threadIdx.x == 0) {
        double cl = 0.0, rl = 0.0;
        for (int b = 0; b < NB; ++b) {
            const int np = npos[b];
            const double d = (double)(np > 1 ? np : 1);
            cl += (cls_sum[b] + corr[b]) / d;
            if (np > 0) rl += reg_sum[b] / (4.0 * (double)np);
        }
        out[0] = (float)(cl / (double)NB);
        out[1] = (float)(rl / (double)NB);
    }
}

extern "C" void kernel_launch(void* const* d_in, const int* in_sizes, int n_in,
                              void* d_out, int out_size, void* d_ws, size_t ws_size,
                              hipStream_t stream) {
    const float* cls = (const float*)d_in[0];   // [NB,NA,NC]
    const float* reg = (const float*)d_in[1];   // [NB,NA,4]
    const float* anc = (const float*)d_in[2];   // [1,NA,4]
    const float* ann = (const float*)d_in[3];   // [NB,NM,5]
    float* out = (float*)d_out;

    char* ws = (char*)d_ws;
    double*   reg_sum   = (double*)(ws + 0);
    double*   cls_sum   = (double*)(ws + 64);
    double*   corr      = (double*)(ws + 128);
    int*      npos      = (int*)(ws + 192);
    int*      pos_count = (int*)(ws + 224);
    float*    wa        = (float*)(ws + 256);
    uint32_t* pos_list  = (uint32_t*)(ws + 256 + 4 * (NB * NA + 16));

    (void)hipMemsetAsync(d_ws, 0, 256, stream);

    dim3 ga((NA + 255) / 256, NB);
    fl_assign<<<ga, 256, 0, stream>>>(anc, reg, ann, reg_sum, npos, pos_count,
                                      wa, pos_list);
    dim3 gf((CHUNKS_IMG + 1023) / 1024, NB);
    fl_focal<<<gf, 256, 0, stream>>>((const f32x4*)cls, wa, cls_sum);
    fl_posfix<<<32, 256, 0, stream>>>(cls, pos_list, pos_count, corr);
    fl_final<<<1, 64, 0, stream>>>(reg_sum, cls_sum, corr, npos, out);
}

// Round 4
// 260.913 us; speedup vs baseline: 2.0719x; 2.0719x over previous
//
#include <hip/hip_runtime.h>
#include <hip/hip_bf16.h>
#include <stdint.h>

// Problem constants (from reference setup_inputs)
#define NB 8
#define NA 49104
#define NC 90
#define NM 32
#define FEPS 1e-4f
#define CHUNKS_IMG (NA * NC / 4)       // 1,104,840 float4 chunks per image
#define LN2_HALF 0.34657359027997264f  // 0.5 * ln(2)
#define CPT 8                          // chunks per thread in fl_focal
#define FBLK ((CHUNKS_IMG + 256 * CPT - 1) / (256 * CPT))  // 540 blocks/image

typedef float f32x4 __attribute__((ext_vector_type(4)));

// ws layout (header zeroed each launch):
//   [0,64)    double reg_sum[8]
//   [64,128)  double cls_sum[8]   (correction folded in)
//   [128,160) int    npos[8]
//   [256,...) uint32 meta[NB*NA + 16]  (bits0-6 label, bit7 pos, bit8 bz)

// ---------------------------------------------------------------------------
// Kernel A: per-anchor IoU assignment -> meta word + smooth-L1 reg sum + npos.
// No compact list, no single-address hot atomics (one atomic per block).
// ---------------------------------------------------------------------------
__global__ __launch_bounds__(256) void fl_assign(
    const float* __restrict__ anchors,      // [NA,4] (y1,x1,y2,x2)
    const float* __restrict__ regressions,  // [NB,NA,4]
    const float* __restrict__ annotations,  // [NB,NM,5] (x1,y1,x2,y2,label)
    double* __restrict__ reg_sum,           // [NB]
    int* __restrict__ npos,                 // [NB]
    uint32_t* __restrict__ meta)            // [NB*NA + pad]
{
    const int b = blockIdx.y;
    const int a = blockIdx.x * 256 + threadIdx.x;

    __shared__ float s_ann[NM * 5];
    if (threadIdx.x < NM * 5)
        s_ann[threadIdx.x] = annotations[b * NM * 5 + threadIdx.x];
    __syncthreads();

    float rsum = 0.0f;
    int pcnt = 0;

    if (a < NA) {
        const f32x4 av = ((const f32x4*)anchors)[a];
        const float ay1 = av.x, ax1 = av.y, ay2 = av.z, ax2 = av.w;
        const float aw = ax2 - ax1, ah = ay2 - ay1;
        const float aarea = aw * ah;

        float best = -2.0f;   // invalid gt iou = -1; strict > keeps first argmax
        int bm = 0;
        #pragma unroll 4
        for (int m = 0; m < NM; ++m) {
            const float bx1 = s_ann[m * 5 + 0];
            const float by1 = s_ann[m * 5 + 1];
            const float bx2 = s_ann[m * 5 + 2];
            const float by2 = s_ann[m * 5 + 3];
            const float lab = s_ann[m * 5 + 4];
            const float area = (bx2 - bx1) * (by2 - by1);
            float iw = fminf(ax2, bx2) - fmaxf(ax1, bx1);
            float ih = fminf(ay2, by2) - fmaxf(ay1, by1);
            iw = fmaxf(iw, 0.0f);
            ih = fmaxf(ih, 0.0f);
            const float inter = iw * ih;
            const float ua = fmaxf(aarea + area - inter, 1e-8f);
            float iou = inter / ua;
            if (lab == -1.0f) iou = -1.0f;
            if (iou > best) { best = iou; bm = m; }
        }

        const bool pos = best >= 0.5f;
        const bool bz = (best < 0.4f) || pos;      // non-ignored anchor
        const int lbl = ((int)s_ann[bm * 5 + 4]) & 0x7f;
        meta[b * NA + a] = (uint32_t)lbl | (pos ? 0x80u : 0u) | (bz ? 0x100u : 0u);

        if (pos) {
            pcnt = 1;
            const float bx1 = s_ann[bm * 5 + 0];
            const float by1 = s_ann[bm * 5 + 1];
            const float bx2 = s_ann[bm * 5 + 2];
            const float by2 = s_ann[bm * 5 + 3];
            float gw = bx2 - bx1, gh = by2 - by1;
            const float gcx = bx1 + 0.5f * gw;
            const float gcy = by1 + 0.5f * gh;    // cx/cy use unclipped w/h
            gw = fmaxf(gw, 1.0f);
            gh = fmaxf(gh, 1.0f);
            const float acx = ax1 + 0.5f * aw;
            const float acy = ay1 + 0.5f * ah;

            const f32x4 rv = ((const f32x4*)regressions)[(size_t)b * NA + a];
            const float t0 = (gcy - acy) / ah;
            const float t1 = (gcx - acx) / aw;
            const float t2 = logf(gh / ah);
            const float t3 = logf(gw / aw);

            float d;
            d = fabsf(t0 - rv.x); rsum += (d <= 1.0f/9.0f) ? 4.5f*d*d : d - 1.0f/18.0f;
            d = fabsf(t1 - rv.y); rsum += (d <= 1.0f/9.0f) ? 4.5f*d*d : d - 1.0f/18.0f;
            d = fabsf(t2 - rv.z); rsum += (d <= 1.0f/9.0f) ? 4.5f*d*d : d - 1.0f/18.0f;
            d = fabsf(t3 - rv.w); rsum += (d <= 1.0f/9.0f) ? 4.5f*d*d : d - 1.0f/18.0f;
        }
    }

    // block reduce (4 waves of 64)
    #pragma unroll
    for (int off = 32; off > 0; off >>= 1) {
        rsum += __shfl_down(rsum, off);
        pcnt += __shfl_down(pcnt, off);
    }
    __shared__ float s_r[4];
    __shared__ int s_p[4];
    const int wave = threadIdx.x >> 6;
    if ((threadIdx.x & 63) == 0) { s_r[wave] = rsum; s_p[wave] = pcnt; }
    __syncthreads();
    if (threadIdx.x == 0) {
        const float r = s_r[0] + s_r[1] + s_r[2] + s_r[3];
        const int p = s_p[0] + s_p[1] + s_p[2] + s_p[3];
        if (p) atomicAdd(&npos[b], p);
        if (r != 0.0f) atomicAdd(&reg_sum[b], (double)r);
    }
}

// ---------------------------------------------------------------------------
// Kernel B: focal pass with the t=1 correction folded in.
// Each thread: 8 independent NT float4 loads in flight, then compute.
// Unified form: pf = match ? 1-p : p; loss = w * pf^2 * log2(1-pf),
// scaled by -0.5*ln2 at the block atomic.  Grid (FBLK, NB), block 256.
// ---------------------------------------------------------------------------
__global__ __launch_bounds__(256) void fl_focal(
    const f32x4* __restrict__ cls,
    const uint32_t* __restrict__ meta,
    double* __restrict__ cls_sum)
{
    const int b = blockIdx.y;
    const f32x4* cb = cls + (size_t)b * CHUNKS_IMG;
    const uint32_t* mb = meta + b * NA;

    const int i0 = blockIdx.x * (256 * CPT) + threadIdx.x;

    // Phase 1: issue all 8 global loads (independent, stay in flight)
    f32x4 v[CPT];
    int   ic[CPT];
    float okf[CPT];
    #pragma unroll
    for (int u = 0; u < CPT; ++u) {
        const int i = i0 + u * 256;
        const bool ok = i < CHUNKS_IMG;
        okf[u] = ok ? 1.0f : 0.0f;
        ic[u] = ok ? i : (CHUNKS_IMG - 1);
        v[u] = __builtin_nontemporal_load(&cb[ic[u]]);
    }

    // Phase 2: per-chunk meta (2 gathers, mostly L1-hit: ~meta reuse x90/4)
    int   c0[CPT], tA[CPT], tB[CPT];
    float wA[CPT], wB[CPT];
    #pragma unroll
    for (int u = 0; u < CPT; ++u) {
        const uint32_t e0 = (uint32_t)ic[u] * 4u;
        const uint32_t aid = e0 / 90u;          // magic-mul division
        c0[u] = (int)(e0 - aid * 90u);
        const uint32_t m0 = mb[aid];
        const uint32_t m1 = mb[aid + 1];        // padded; garbage ok (unselected)
        wA[u] = ((m0 & 0x100u) ? 1.0f : 0.0f) * okf[u];
        wB[u] = ((m1 & 0x100u) ? 1.0f : 0.0f) * okf[u];
        tA[u] = (m0 & 0x80u) ? (int)(m0 & 0x7fu) : 0x7fff;        // no-match sentinel
        tB[u] = ((m1 & 0x80u) ? (int)(m1 & 0x7fu) : 0x7fff) + 90; // shifted to cc space
    }

    // Phase 3: compute
    float acc = 0.0f;
    #pragma unroll
    for (int u = 0; u < CPT; ++u) {
        const float pv[4] = {v[u].x, v[u].y, v[u].z, v[u].w};
        #pragma unroll
        for (int j = 0; j < 4; ++j) {
            const int cc = c0[u] + j;
            const bool inA = cc < 90;
            const float w = inA ? wA[u] : wB[u];
            const int tgt = inA ? tA[u] : tB[u];
            float p = fminf(fmaxf(pv[j], FEPS), 1.0f - FEPS);
            const float pf = (cc == tgt) ? 1.0f - p : p;
            const float l = __log2f(1.0f - pf);
            acc = fmaf(pf * pf * l, w, acc);
        }
    }

    #pragma unroll
    for (int off = 32; off > 0; off >>= 1)
        acc += __shfl_down(acc, off);
    __shared__ float s_r[4];
    const int wave = threadIdx.x >> 6;
    if ((threadIdx.x & 63) == 0) s_r[wave] = acc;
    __syncthreads();
    if (threadIdx.x == 0) {
        const float r = s_r[0] + s_r[1] + s_r[2] + s_r[3];
        atomicAdd(&cls_sum[b], (double)r * -(double)LN2_HALF);
    }
}

// ---------------------------------------------------------------------------
// Kernel C: finalize
// ---------------------------------------------------------------------------
__global__ void fl_final(
    const double* __restrict__ reg_sum,
    const double* __restrict__ cls_sum,
    const int* __restrict__ npos,
    float* __restrict__ out)
{
    if (threadIdx.x == 0) {
        double cl = 0.0, rl = 0.0;
        for (int b = 0; b < NB; ++b) {
            const int np = npos[b];
            const double d = (double)(np > 1 ? np : 1);
            cl += cls_sum[b] / d;
            if (np > 0) rl += reg_sum[b] / (4.0 * (double)np);
        }
        out[0] = (float)(cl / (double)NB);
        out[1] = (float)(rl / (double)NB);
    }
}

extern "C" void kernel_launch(void* const* d_in, const int* in_sizes, int n_in,
                              void* d_out, int out_size, void* d_ws, size_t ws_size,
                              hipStream_t stream) {
    const float* cls = (const float*)d_in[0];   // [NB,NA,NC]
    const float* reg = (const float*)d_in[1];   // [NB,NA,4]
    const float* anc = (const float*)d_in[2];   // [1,NA,4]
    const float* ann = (const float*)d_in[3];   // [NB,NM,5]
    float* out = (float*)d_out;

    char* ws = (char*)d_ws;
    double*   reg_sum = (double*)(ws + 0);
    double*   cls_sum = (double*)(ws + 64);
    int*      npos    = (int*)(ws + 128);
    uint32_t* meta    = (uint32_t*)(ws + 256);  // NB*NA+16 words

    (void)hipMemsetAsync(d_ws, 0, 256, stream);

    dim3 ga((NA + 255) / 256, NB);
    fl_assign<<<ga, 256, 0, stream>>>(anc, reg, ann, reg_sum, npos, meta);
    dim3 gf(FBLK, NB);
    fl_focal<<<gf, 256, 0, stream>>>((const f32x4*)cls, meta, cls_sum);
    fl_final<<<1, 64, 0, stream>>>(reg_sum, cls_sum, npos, out);
}

// Round 5
// 214.379 us; speedup vs baseline: 2.5217x; 1.2171x over previous
//
#include <hip/hip_runtime.h>
#include <stdint.h>

// Problem constants (from reference setup_inputs)
#define NB 8
#define NA 49104
#define NC 90
#define NM 32
#define FEPS 1e-4f
#define APB 256                        // anchors per block
#define GX ((NA + APB - 1) / APB)      // 192 blocks per image
#define CPB (APB * NC / 4)             // 5760 float4 chunks per block
#define CHUNKS_IMG (NA * NC / 4)       // 1,104,840 chunks per image
#define LN2_HALF 0.34657359027997264   // 0.5 * ln(2)

typedef float f32x4 __attribute__((ext_vector_type(4)));

// ws layout (no zeroing needed — every slot written unconditionally):
//   [0,6144)      float cls_p[NB*GX]   (block partial, log2 units)
//   [8192,14336)  float reg_p[NB*GX]
//   [16384,22528) int   np_p [NB*GX]

// ---------------------------------------------------------------------------
// Focal inner: N chunks starting at chunk (cstart + t) within the block.
// Meta comes from LDS (s_w = 0/1 weight, s_t = target class or 0x7fff).
// Loss form (covers t=0 and t=1): pf = (c==tgt)?1-p:p; w*pf^2*log2(1-pf).
// ---------------------------------------------------------------------------
template<int N>
__device__ inline float focal_group(const f32x4* __restrict__ ci, int gbase,
                                    int cstart, int t,
                                    const float* s_w, const int* s_t)
{
    f32x4 v[N];
    int   cl[N];
    float vf[N];
    #pragma unroll
    for (int u = 0; u < N; ++u) {
        const int c = cstart + u * 256 + t;
        vf[u] = (c < CPB) ? 1.0f : 0.0f;
        cl[u] = (c < CPB) ? c : (CPB - 1);
        int ic = gbase + cl[u];
        ic = (ic < CHUNKS_IMG) ? ic : (CHUNKS_IMG - 1);
        v[u] = ci[ic];
    }
    float acc = 0.0f;
    #pragma unroll
    for (int u = 0; u < N; ++u) {
        const int e0   = cl[u] * 4;                  // < 23040
        const int aidl = (e0 * 46604) >> 22;         // exact /90 for e0 < 23040
        const int c0   = e0 - aidl * 90;
        const float w0 = s_w[aidl]     * vf[u];
        const float w1 = s_w[aidl + 1] * vf[u];
        const int   t0 = s_t[aidl];
        const int   t1 = s_t[aidl + 1] + 90;         // shifted into cc space
        const float pv[4] = {v[u].x, v[u].y, v[u].z, v[u].w};
        #pragma unroll
        for (int j = 0; j < 4; ++j) {
            const int cc  = c0 + j;
            const bool inA = cc < 90;
            const float w  = inA ? w0 : w1;
            const int  tgt = inA ? t0 : t1;
            float p = fminf(fmaxf(pv[j], FEPS), 1.0f - FEPS);
            const float pf = (cc == tgt) ? 1.0f - p : p;
            const float l  = __log2f(1.0f - pf);
            acc = fmaf(pf * pf * l, w, acc);
        }
    }
    return acc;
}

// ---------------------------------------------------------------------------
// Fused kernel: phase 1 = IoU assignment for this block's 256 anchors (meta
// to LDS, smooth-L1 reg sum, npos count); phase 2 = focal over the block's
// 5760 cls chunks. One partial-slot write per block, no atomics.
// ---------------------------------------------------------------------------
__global__ __launch_bounds__(256) void fl_fused(
    const float* __restrict__ anchors,      // [NA,4] (y1,x1,y2,x2)
    const f32x4* __restrict__ cls,          // [NB, CHUNKS_IMG]
    const float* __restrict__ regressions,  // [NB,NA,4]
    const float* __restrict__ annotations,  // [NB,NM,5] (x1,y1,x2,y2,label)
    float* __restrict__ cls_p,
    float* __restrict__ reg_p,
    int* __restrict__ np_p)
{
    const int bx = blockIdx.x;
    const int b  = blockIdx.y;
    const int t  = threadIdx.x;

    __shared__ float s_ann[NM * 5];
    __shared__ float s_w[APB + 1];
    __shared__ int   s_t[APB + 1];

    if (t < NM * 5)
        s_ann[t] = annotations[b * NM * 5 + t];
    __syncthreads();

    // ---- phase 1: anchor assignment ----
    const int a = bx * APB + t;
    float rsum = 0.0f;
    int   pcnt = 0;
    float wv = 0.0f;
    int   tv = 0x7fff;

    if (a < NA) {
        const f32x4 av = ((const f32x4*)anchors)[a];
        const float ay1 = av.x, ax1 = av.y, ay2 = av.z, ax2 = av.w;
        const float aw = ax2 - ax1, ah = ay2 - ay1;
        const float aarea = aw * ah;

        float best = -2.0f;   // invalid gt iou = -1; strict > keeps first argmax
        int bm = 0;
        #pragma unroll 4
        for (int m = 0; m < NM; ++m) {
            const float bx1 = s_ann[m * 5 + 0];
            const float by1 = s_ann[m * 5 + 1];
            const float bx2 = s_ann[m * 5 + 2];
            const float by2 = s_ann[m * 5 + 3];
            const float lab = s_ann[m * 5 + 4];
            const float area = (bx2 - bx1) * (by2 - by1);
            float iw = fminf(ax2, bx2) - fmaxf(ax1, bx1);
            float ih = fminf(ay2, by2) - fmaxf(ay1, by1);
            iw = fmaxf(iw, 0.0f);
            ih = fmaxf(ih, 0.0f);
            const float inter = iw * ih;
            const float ua = fmaxf(aarea + area - inter, 1e-8f);
            float iou = inter / ua;
            if (lab == -1.0f) iou = -1.0f;
            if (iou > best) { best = iou; bm = m; }
        }

        const bool pos = best >= 0.5f;
        const bool bz  = (best < 0.4f) || pos;     // non-ignored anchor
        wv = bz ? 1.0f : 0.0f;
        tv = pos ? (((int)s_ann[bm * 5 + 4]) & 0x7f) : 0x7fff;

        if (pos) {
            pcnt = 1;
            const float bx1 = s_ann[bm * 5 + 0];
            const float by1 = s_ann[bm * 5 + 1];
            const float bx2 = s_ann[bm * 5 + 2];
            const float by2 = s_ann[bm * 5 + 3];
            float gw = bx2 - bx1, gh = by2 - by1;
            const float gcx = bx1 + 0.5f * gw;     // centers use unclipped w/h
            const float gcy = by1 + 0.5f * gh;
            gw = fmaxf(gw, 1.0f);
            gh = fmaxf(gh, 1.0f);
            const float acx = ax1 + 0.5f * aw;
            const float acy = ay1 + 0.5f * ah;

            const f32x4 rv = ((const f32x4*)regressions)[(size_t)b * NA + a];
            const float t0 = (gcy - acy) / ah;
            const float t1 = (gcx - acx) / aw;
            const float t2 = logf(gh / ah);
            const float t3 = logf(gw / aw);

            float d;
            d = fabsf(t0 - rv.x); rsum += (d <= 1.0f/9.0f) ? 4.5f*d*d : d - 1.0f/18.0f;
            d = fabsf(t1 - rv.y); rsum += (d <= 1.0f/9.0f) ? 4.5f*d*d : d - 1.0f/18.0f;
            d = fabsf(t2 - rv.z); rsum += (d <= 1.0f/9.0f) ? 4.5f*d*d : d - 1.0f/18.0f;
            d = fabsf(t3 - rv.w); rsum += (d <= 1.0f/9.0f) ? 4.5f*d*d : d - 1.0f/18.0f;
        }
    }

    s_w[t] = wv;
    s_t[t] = tv;
    if (t == 0) { s_w[APB] = 0.0f; s_t[APB] = 0x7fff; }
    __syncthreads();

    // ---- phase 2: focal over this block's chunks (8+8+7 pipelined groups) ----
    const f32x4* ci = cls + (size_t)b * CHUNKS_IMG;
    const int gbase = bx * CPB;

    float acc;
    acc  = focal_group<8>(ci, gbase, 0,    t, s_w, s_t);
    acc += focal_group<8>(ci, gbase, 2048, t, s_w, s_t);
    acc += focal_group<7>(ci, gbase, 4096, t, s_w, s_t);

    // ---- block reduce: acc, rsum, pcnt ----
    #pragma unroll
    for (int off = 32; off; off >>= 1) {
        acc  += __shfl_down(acc, off);
        rsum += __shfl_down(rsum, off);
        pcnt += __shfl_down(pcnt, off);
    }
    __shared__ float sa[4], sr[4];
    __shared__ int   sp[4];
    const int wid = t >> 6;
    if ((t & 63) == 0) { sa[wid] = acc; sr[wid] = rsum; sp[wid] = pcnt; }
    __syncthreads();
    if (t == 0) {
        const int slot = b * GX + bx;
        cls_p[slot] = sa[0] + sa[1] + sa[2] + sa[3];
        reg_p[slot] = sr[0] + sr[1] + sr[2] + sr[3];
        np_p[slot]  = sp[0] + sp[1] + sp[2] + sp[3];
    }
}

// ---------------------------------------------------------------------------
// Finalize: 1 block, 256 threads = 8 images x 32 lanes; each lane sums 6
// slots, 32-lane shuffle reduce, thread 0 combines in double.
// ---------------------------------------------------------------------------
__global__ __launch_bounds__(256) void fl_final(
    const float* __restrict__ cls_p,
    const float* __restrict__ reg_p,
    const int* __restrict__ np_p,
    float* __restrict__ out)
{
    const int t = threadIdx.x;
    const int img = t >> 5, lane = t & 31;

    float cs = 0.0f, rs = 0.0f;
    int ns = 0;
    #pragma unroll
    for (int k = 0; k < GX / 32; ++k) {   // 6 slots per lane
        const int s = img * GX + k * 32 + lane;
        cs += cls_p[s];
        rs += reg_p[s];
        ns += np_p[s];
    }
    #pragma unroll
    for (int off = 16; off; off >>= 1) {  // stays within the 32-lane group
        cs += __shfl_down(cs, off);
        rs += __shfl_down(rs, off);
        ns += __shfl_down(ns, off);
    }
    __shared__ double s_c[8], s_r[8];
    __shared__ int    s_n[8];
    if (lane == 0) { s_c[img] = (double)cs; s_r[img] = (double)rs; s_n[img] = ns; }
    __syncthreads();
    if (t == 0) {
        double cl = 0.0, rl = 0.0;
        for (int b = 0; b < NB; ++b) {
            const int np = s_n[b];
            cl += s_c[b] * (-LN2_HALF) / (double)(np > 1 ? np : 1);
            if (np > 0) rl += s_r[b] / (4.0 * (double)np);
        }
        out[0] = (float)(cl / (double)NB);
        out[1] = (float)(rl / (double)NB);
    }
}

extern "C" void kernel_launch(void* const* d_in, const int* in_sizes, int n_in,
                              void* d_out, int out_size, void* d_ws, size_t ws_size,
                              hipStream_t stream) {
    const float* cls = (const float*)d_in[0];   // [NB,NA,NC]
    const float* reg = (const float*)d_in[1];   // [NB,NA,4]
    const float* anc = (const float*)d_in[2];   // [1,NA,4]
    const float* ann = (const float*)d_in[3];   // [NB,NM,5]
    float* out = (float*)d_out;

    char* ws = (char*)d_ws;
    float* cls_p = (float*)(ws + 0);
    float* reg_p = (float*)(ws + 8192);
    int*   np_p  = (int*)(ws + 16384);

    dim3 g(GX, NB);
    fl_fused<<<g, 256, 0, stream>>>(anc, (const f32x4*)cls, reg, ann,
                                    cls_p, reg_p, np_p);
    fl_final<<<1, 256, 0, stream>>>(cls_p, reg_p, np_p, out);
}